// Round 1
// baseline (54.714 us; speedup 1.0000x reference)
//
#include <hip/hip_runtime.h>

// Problem constants (from reference setup_inputs): h_all [T,B,D] fp32
#define T_DIM 2048
#define B_DIM 64
#define D_DIM 512
#define CHUNKS 32                         // t-chunks per batch
#define ROWS_PER_BLOCK (T_DIM / CHUNKS)   // 64 rows of h per block
#define NWAVES 4                          // 256 threads
#define ROWS_PER_WAVE (ROWS_PER_BLOCK / NWAVES)  // 16
#define RSQRT_D 0.044194173824159216f     // 1/sqrt(512)

// Pass 1: per (b, t-chunk) block, accumulate partial numerator N[b,0:512]
// and denominator S[b] with a single read of each h row.
__global__ __launch_bounds__(256)
void ap_partial_kernel(const float* __restrict__ h,
                       float* __restrict__ Nacc,
                       float* __restrict__ Sacc)
{
    const int b     = blockIdx.x % B_DIM;
    const int chunk = blockIdx.x / B_DIM;
    const int tid   = threadIdx.x;
    const int wave  = tid >> 6;
    const int lane  = tid & 63;

    const size_t rowStride = (size_t)B_DIM * D_DIM;   // floats between t's

    // h_last[b] fragment for this lane: d = lane*8 .. lane*8+7 (registers)
    const float* hl = h + (size_t)(T_DIM - 1) * rowStride + (size_t)b * D_DIM + lane * 8;
    const float4 hl0 = ((const float4*)hl)[0];
    const float4 hl1 = ((const float4*)hl)[1];

    float acc0 = 0.f, acc1 = 0.f, acc2 = 0.f, acc3 = 0.f;
    float acc4 = 0.f, acc5 = 0.f, acc6 = 0.f, acc7 = 0.f;
    float s = 0.f;

    const int t0 = chunk * ROWS_PER_BLOCK + wave * ROWS_PER_WAVE;
    const float* base = h + (size_t)t0 * rowStride + (size_t)b * D_DIM + lane * 8;

    #pragma unroll 4
    for (int i = 0; i < ROWS_PER_WAVE; ++i) {
        const float* p = base + (size_t)i * rowStride;
        const float4 v0 = ((const float4*)p)[0];
        const float4 v1 = ((const float4*)p)[1];

        // per-lane partial dot over its 8 elements
        float dp;
        dp = v0.x * hl0.x;
        dp = fmaf(v0.y, hl0.y, dp);
        dp = fmaf(v0.z, hl0.z, dp);
        dp = fmaf(v0.w, hl0.w, dp);
        dp = fmaf(v1.x, hl1.x, dp);
        dp = fmaf(v1.y, hl1.y, dp);
        dp = fmaf(v1.z, hl1.z, dp);
        dp = fmaf(v1.w, hl1.w, dp);

        // 64-lane butterfly reduce (wave = 64 on CDNA)
        #pragma unroll
        for (int m = 1; m < 64; m <<= 1)
            dp += __shfl_xor(dp, m, 64);

        const float r = fmaxf(dp * RSQRT_D, 0.f);

        acc0 = fmaf(r, v0.x, acc0);
        acc1 = fmaf(r, v0.y, acc1);
        acc2 = fmaf(r, v0.z, acc2);
        acc3 = fmaf(r, v0.w, acc3);
        acc4 = fmaf(r, v1.x, acc4);
        acc5 = fmaf(r, v1.y, acc5);
        acc6 = fmaf(r, v1.z, acc6);
        acc7 = fmaf(r, v1.w, acc7);
        s += r;   // r is wave-uniform after reduce
    }

    // Cross-wave reduce in LDS, then one atomicAdd per (d) per block.
    __shared__ float accs[NWAVES][D_DIM];   // 8 KiB
    __shared__ float ssum[NWAVES];

    float4* dstA = (float4*)&accs[wave][lane * 8];
    dstA[0] = make_float4(acc0, acc1, acc2, acc3);
    dstA[1] = make_float4(acc4, acc5, acc6, acc7);
    if (lane == 0) ssum[wave] = s;
    __syncthreads();

    #pragma unroll
    for (int k = 0; k < 2; ++k) {
        const int d = tid + k * 256;
        const float v = accs[0][d] + accs[1][d] + accs[2][d] + accs[3][d];
        atomicAdd(&Nacc[(size_t)b * D_DIM + d], v);
    }
    if (tid == 0) {
        atomicAdd(&Sacc[b], ssum[0] + ssum[1] + ssum[2] + ssum[3]);
    }
}

// Pass 2: out[b,d] = N[b,d] / (S[b] + 1e-9)
__global__ __launch_bounds__(512)
void ap_finalize_kernel(const float* __restrict__ Nacc,
                        const float* __restrict__ Sacc,
                        float* __restrict__ out)
{
    const int b = blockIdx.x;
    const int d = threadIdx.x;
    out[(size_t)b * D_DIM + d] = Nacc[(size_t)b * D_DIM + d] / (Sacc[b] + 1e-9f);
}

extern "C" void kernel_launch(void* const* d_in, const int* in_sizes, int n_in,
                              void* d_out, int out_size, void* d_ws, size_t ws_size,
                              hipStream_t stream)
{
    const float* h = (const float*)d_in[0];   // h_all [T,B,D] fp32; xin (d_in[1]) unused
    float* ws   = (float*)d_ws;
    float* Nacc = ws;                         // [B, D]
    float* Sacc = ws + (size_t)B_DIM * D_DIM; // [B]

    // Must zero accumulators EVERY call (harness doesn't re-poison between replays).
    hipMemsetAsync(d_ws, 0, ((size_t)B_DIM * D_DIM + B_DIM) * sizeof(float), stream);

    ap_partial_kernel<<<B_DIM * CHUNKS, 256, 0, stream>>>(h, Nacc, Sacc);
    ap_finalize_kernel<<<B_DIM, 512, 0, stream>>>(Nacc, Sacc, (float*)d_out);
}

// Round 2
// 51.758 us; speedup vs baseline: 1.0571x; 1.0571x over previous
//
#include <hip/hip_runtime.h>

// Problem constants (from reference setup_inputs): h_all [T,B,D] fp32
#define T_DIM 2048
#define B_DIM 64
#define D_DIM 512
#define CHUNKS 32                         // t-chunks per batch
#define ROWS_PER_BLOCK (T_DIM / CHUNKS)   // 64 rows of h per block
#define NWAVES 4                          // 256 threads
#define ROWS_PER_WAVE (ROWS_PER_BLOCK / NWAVES)  // 16
#define RSQRT_D 0.044194173824159216f     // 1/sqrt(512)

// Pass 1: per (b, t-chunk) block, compute partial numerator P[chunk][b][0:512]
// and partial denominator S[chunk][b] with a single read of each h row.
// Plain stores (no atomics); workspace fully overwritten each call, so no
// memset is needed and replays are bit-exact deterministic.
__global__ __launch_bounds__(256)
void ap_partial_kernel(const float* __restrict__ h,
                       float* __restrict__ Ppart,   // [CHUNKS][B][D]
                       float* __restrict__ Spart)   // [CHUNKS][B]
{
    const int b     = blockIdx.x % B_DIM;
    const int chunk = blockIdx.x / B_DIM;
    const int tid   = threadIdx.x;
    const int wave  = tid >> 6;
    const int lane  = tid & 63;

    const size_t rowStride = (size_t)B_DIM * D_DIM;   // floats between t's

    // h_last[b] fragment for this lane: d = lane*8 .. lane*8+7 (registers)
    const float* hl = h + (size_t)(T_DIM - 1) * rowStride + (size_t)b * D_DIM + lane * 8;
    const float4 hl0 = ((const float4*)hl)[0];
    const float4 hl1 = ((const float4*)hl)[1];

    float acc0 = 0.f, acc1 = 0.f, acc2 = 0.f, acc3 = 0.f;
    float acc4 = 0.f, acc5 = 0.f, acc6 = 0.f, acc7 = 0.f;
    float s = 0.f;

    const int t0 = chunk * ROWS_PER_BLOCK + wave * ROWS_PER_WAVE;
    const float* base = h + (size_t)t0 * rowStride + (size_t)b * D_DIM + lane * 8;

    #pragma unroll 4
    for (int i = 0; i < ROWS_PER_WAVE; ++i) {
        const float* p = base + (size_t)i * rowStride;
        const float4 v0 = ((const float4*)p)[0];
        const float4 v1 = ((const float4*)p)[1];

        // per-lane partial dot over its 8 elements
        float dp;
        dp = v0.x * hl0.x;
        dp = fmaf(v0.y, hl0.y, dp);
        dp = fmaf(v0.z, hl0.z, dp);
        dp = fmaf(v0.w, hl0.w, dp);
        dp = fmaf(v1.x, hl1.x, dp);
        dp = fmaf(v1.y, hl1.y, dp);
        dp = fmaf(v1.z, hl1.z, dp);
        dp = fmaf(v1.w, hl1.w, dp);

        // 64-lane butterfly reduce (wave = 64 on CDNA)
        #pragma unroll
        for (int m = 1; m < 64; m <<= 1)
            dp += __shfl_xor(dp, m, 64);

        const float r = fmaxf(dp * RSQRT_D, 0.f);

        acc0 = fmaf(r, v0.x, acc0);
        acc1 = fmaf(r, v0.y, acc1);
        acc2 = fmaf(r, v0.z, acc2);
        acc3 = fmaf(r, v0.w, acc3);
        acc4 = fmaf(r, v1.x, acc4);
        acc5 = fmaf(r, v1.y, acc5);
        acc6 = fmaf(r, v1.z, acc6);
        acc7 = fmaf(r, v1.w, acc7);
        s += r;   // r is wave-uniform after reduce
    }

    // Cross-wave reduce in LDS, then plain stores of this block's partial.
    __shared__ float accs[NWAVES][D_DIM];   // 8 KiB
    __shared__ float ssum[NWAVES];

    float4* dstA = (float4*)&accs[wave][lane * 8];
    dstA[0] = make_float4(acc0, acc1, acc2, acc3);
    dstA[1] = make_float4(acc4, acc5, acc6, acc7);
    if (lane == 0) ssum[wave] = s;
    __syncthreads();

    const size_t pbase = ((size_t)chunk * B_DIM + b) * D_DIM;
    #pragma unroll
    for (int k = 0; k < 2; ++k) {
        const int d = tid + k * 256;
        Ppart[pbase + d] = accs[0][d] + accs[1][d] + accs[2][d] + accs[3][d];
    }
    if (tid == 0) {
        Spart[chunk * B_DIM + b] = ssum[0] + ssum[1] + ssum[2] + ssum[3];
    }
}

// Pass 2: out[b,d] = sum_c P[c][b][d] / (sum_c S[c][b] + 1e-9)
// Partials are hot in L2; fixed summation order -> deterministic.
__global__ __launch_bounds__(512)
void ap_reduce_kernel(const float* __restrict__ Ppart,
                      const float* __restrict__ Spart,
                      float* __restrict__ out)
{
    const int b = blockIdx.x;
    const int d = threadIdx.x;

    // Denominator: block-uniform addresses -> compiler scalarizes these loads.
    float s = 0.f;
    #pragma unroll
    for (int c = 0; c < CHUNKS; ++c)
        s += Spart[c * B_DIM + b];

    float acc = 0.f;
    #pragma unroll
    for (int c = 0; c < CHUNKS; ++c)
        acc += Ppart[((size_t)c * B_DIM + b) * D_DIM + d];

    out[(size_t)b * D_DIM + d] = acc / (s + 1e-9f);
}

extern "C" void kernel_launch(void* const* d_in, const int* in_sizes, int n_in,
                              void* d_out, int out_size, void* d_ws, size_t ws_size,
                              hipStream_t stream)
{
    const float* h = (const float*)d_in[0];   // h_all [T,B,D] fp32; xin (d_in[1]) unused
    float* ws    = (float*)d_ws;
    float* Ppart = ws;                                      // [CHUNKS][B][D]
    float* Spart = ws + (size_t)CHUNKS * B_DIM * D_DIM;     // [CHUNKS][B]

    ap_partial_kernel<<<B_DIM * CHUNKS, 256, 0, stream>>>(h, Ppart, Spart);
    ap_reduce_kernel<<<B_DIM, 512, 0, stream>>>(Ppart, Spart, (float*)d_out);
}